// Round 2
// baseline (496.637 us; speedup 1.0000x reference)
//
#include <hip/hip_runtime.h>
#include <stdint.h>

#define LBL 50
#define NL 52
#define L2E 1.4426950408889634f
#define BB 128
#define SS 512
#define DD 1024

typedef __attribute__((ext_vector_type(8))) short short8;
typedef __attribute__((ext_vector_type(4))) float float4v;
typedef __attribute__((ext_vector_type(2))) float float2v;

union S8U { unsigned int u[4]; short8 s; };

static __device__ __forceinline__ unsigned int f2bf(float f) {
    union { float f; unsigned int u; } v; v.f = f;
    unsigned int r = v.u + 0x7fffu + ((v.u >> 16) & 1u);
    return r >> 16;
}

// ---------------------------------------------------------------------------
// Kernel 0: W [50,1024] f32 -> Wbf [64,1024] bf16 (rows 50..63 zero), rounded.
// ---------------------------------------------------------------------------
__global__ __launch_bounds__(256) void wconv(
    const float* __restrict__ W, unsigned short* __restrict__ Wbf)
{
    int i = blockIdx.x * 256 + threadIdx.x;   // 0..65535
    int r = i >> 10, c = i & 1023;
    float v = (r < LBL) ? W[r * DD + c] : 0.f;
    Wbf[i] = (unsigned short)f2bf(v);
}

// ---------------------------------------------------------------------------
// Kernel 1: PEp[r, c] = exp(sum_d A[r,d]*W[c,d] + b[c]) for c<50, else 0.
// Padded [r][64] output. LDS-free: A-frags straight from global (trunc-pack
// via v_perm), B-frags from pre-converted Wbf (L2-resident).
// ---------------------------------------------------------------------------
__global__ __launch_bounds__(256) void gemm_pe(
    const float* __restrict__ A,            // [65536,1024]
    const unsigned short* __restrict__ Wbf, // [64,1024] bf16
    const float* __restrict__ bias,         // [50]
    float* __restrict__ PEp)                // [65536,64]
{
    const int tid  = threadIdx.x;
    const int lane = tid & 63;
    const int wv   = tid >> 6;
    const int mrow = lane & 15;
    const int quad = lane >> 4;
    const int row  = blockIdx.x * 64 + wv * 16 + mrow;

    const uint4* arow = (const uint4*)(A + (size_t)row * DD);

    float4v acc[4];
#pragma unroll
    for (int i = 0; i < 4; ++i) acc[i] = (float4v){0.f, 0.f, 0.f, 0.f};

#pragma unroll 4
    for (int kc = 0; kc < DD; kc += 32) {
        uint4 u0 = arow[(kc >> 2) + quad * 2];
        uint4 u1 = arow[(kc >> 2) + quad * 2 + 1];
        S8U a;
        a.u[0] = __builtin_amdgcn_perm(u0.y, u0.x, 0x07060302u);
        a.u[1] = __builtin_amdgcn_perm(u0.w, u0.z, 0x07060302u);
        a.u[2] = __builtin_amdgcn_perm(u1.y, u1.x, 0x07060302u);
        a.u[3] = __builtin_amdgcn_perm(u1.w, u1.z, 0x07060302u);
#pragma unroll
        for (int nt = 0; nt < 4; ++nt) {
            short8 bf = *(const short8*)(Wbf + (size_t)(nt * 16 + mrow) * DD + kc + quad * 8);
            acc[nt] = __builtin_amdgcn_mfma_f32_16x16x32_bf16(a.s, bf, acc[nt], 0, 0, 0);
        }
    }
    // epilogue: C[row=quad*4+r][col=nt*16+mrow]
    const int r0 = blockIdx.x * 64 + wv * 16 + quad * 4;
#pragma unroll
    for (int nt = 0; nt < 4; ++nt) {
        int col = nt * 16 + mrow;
        float bv = (col < LBL) ? bias[col] : 0.f;
#pragma unroll
        for (int rr = 0; rr < 4; ++rr) {
            float val = (col < LBL) ? __builtin_amdgcn_exp2f((acc[nt][rr] + bv) * L2E) : 0.f;
            PEp[(size_t)(r0 + rr) * 64 + col] = val;
        }
    }
}

// ---------------------------------------------------------------------------
// Kernel 2: MFMA-batched CRF forward, 8 blocks x 16 chains.
//
// sigma-permuted constant A operand (see R1): MFMA C output at lane (b,q),
// acc[it][r] == label q*8+r+4*(it&1)+32*(it>>1) == next step's B-fragment
// slot -> lane-local repack, no bpermute on the alpha path.
//
// R2 changes (latency attack on the 558 cyc/step serial cycle):
//  * PE prefetch ring deepened 4 -> 8 (slack 8 steps; with 16 waves on the
//    chip there is no TLP, step time settles at L_mem/ring_depth if the
//    ring is the binder).
//  * q = PC*s precomputed OFF the dependent cycle (s is known at step
//    start from the previous step's exponent bpermute; PC loaded 8 steps
//    ago). On-path E-update is now acc*q (16 muls) + 8 v_perm only.
// Numerics bit-identical to R1 (same mul sequence, (PC*s) was already two
// separate muls).
// ---------------------------------------------------------------------------
__global__ __launch_bounds__(128) void crf_fwd(
    const float* __restrict__ PE,     // [65536,64] padded exp(logits)
    const float* __restrict__ T,      // [52,52]
    const int*   __restrict__ lens,   // [128]
    const int*   __restrict__ labels, // [128,512]
    float* __restrict__ out)          // [1], pre-zeroed
{
    const int g    = blockIdx.x;
    const int tid  = threadIdx.x;
    const int lane = tid & 63;
    const int wv   = tid >> 6;
    const int b    = lane & 15;
    const int q    = lane >> 4;

    __shared__ float gold_sh[16];
    float norm_e = 0.f;

    if (wv == 0) {
        const int bb   = g * 16 + b;
        const int lenl = lens[bb];

        // constant A-frags: sigma-permuted e^T rows; A[m=lane&15][k=q*8+reg]
        short8 afr[4][2];
#pragma unroll
        for (int it = 0; it < 4; ++it) {
            int i = (b >> 2) * 8 + (b & 3) + 4 * (it & 1) + 32 * (it >> 1);
#pragma unroll
            for (int jt = 0; jt < 2; ++jt) {
                S8U pk;
#pragma unroll
                for (int h = 0; h < 4; ++h) {
                    int k0 = jt * 32 + q * 8 + 2 * h;
                    float v0 = (i < NL && k0     < NL) ? __builtin_amdgcn_exp2f(T[i * NL + k0]     * L2E) : 0.f;
                    float v1 = (i < NL && k0 + 1 < NL) ? __builtin_amdgcn_exp2f(T[i * NL + k0 + 1] * L2E) : 0.f;
                    pk.u[h] = f2bf(v0) | (f2bf(v1) << 16);
                }
                afr[it][jt] = pk.s;
            }
        }

        const int addrB = b * 4;

        // per-lane PE base: labels [q*8, q*8+8) and [32+q*8, 32+q*8+8)
        const float4* lb = (const float4*)(PE + (size_t)bb * SS * 64 + q * 8);

#define LOADP4(dst, trow) do {                                           \
        const float4* _p = lb + (size_t)(trow) * 16;                     \
        float4 _a0 = _p[0], _a1 = _p[1], _a2 = _p[8], _a3 = _p[9];       \
        dst[0]=_a0.x;  dst[1]=_a0.y;  dst[2]=_a0.z;  dst[3]=_a0.w;       \
        dst[4]=_a1.x;  dst[5]=_a1.y;  dst[6]=_a1.z;  dst[7]=_a1.w;       \
        dst[8]=_a2.x;  dst[9]=_a2.y;  dst[10]=_a2.z; dst[11]=_a2.w;      \
        dst[12]=_a3.x; dst[13]=_a3.y; dst[14]=_a3.z; dst[15]=_a3.w;      \
    } while (0)

        // init E_1[slot] = PE[row0][sigma(slot)] * e^{T[sigma(slot)][START]}
        float E[16];
        {
            float p0[16];
            LOADP4(p0, 0);
#pragma unroll
            for (int k = 0; k < 16; ++k) {
                int it = k >> 2, r = k & 3;
                int i = q * 8 + r + 4 * (it & 1) + 32 * (it >> 1);
                float ets = (i < NL) ? __builtin_amdgcn_exp2f(T[i * NL + LBL] * L2E) : 0.f;
                E[k] = p0[k] * ets;
            }
        }

        // depth-8 register ring
        float r0[16], r1[16], r2[16], r3[16], r4[16], r5[16], r6[16], r7[16];
        LOADP4(r0, 1); LOADP4(r1, 2); LOADP4(r2, 3); LOADP4(r3, 4);
        LOADP4(r4, 5); LOADP4(r5, 6); LOADP4(r6, 7); LOADP4(r7, 8);

        float ncap = 1.0f;
        int lcap = 0, lsum = 0, ebp = 127;

#define STEP(PC, t) do {                                                          \
        /* lane-local C->B repack: bfr[jt] = E slots [8jt .. 8jt+7] (on path) */  \
        S8U bfr[2];                                                               \
        _Pragma("unroll")                                                         \
        for (int jt = 0; jt < 2; ++jt) {                                          \
            _Pragma("unroll")                                                     \
            for (int u = 0; u < 4; ++u) {                                         \
                bfr[jt].u[u] = __builtin_amdgcn_perm(                             \
                    __float_as_uint(E[jt * 8 + 2 * u + 1]),                       \
                    __float_as_uint(E[jt * 8 + 2 * u]), 0x07060302u);             \
            }                                                                     \
        }                                                                         \
        /* off-path: scale from prev step's exponent bpermute; q = PC*s */       \
        int lsum_pre = lsum;                                                      \
        float s = __uint_as_float((unsigned int)(254 - ebp) << 23);               \
        lsum += 127 - ebp;                                                        \
        const float4v zz = (float4v){0.f, 0.f, 0.f, 0.f};                         \
        float4v acc[4];                                                           \
        _Pragma("unroll")                                                         \
        for (int it = 0; it < 4; ++it) {                                          \
            float4v a0 = __builtin_amdgcn_mfma_f32_16x16x32_bf16(afr[it][0], bfr[0].s, zz, 0, 0, 0); \
            acc[it]    = __builtin_amdgcn_mfma_f32_16x16x32_bf16(afr[it][1], bfr[1].s, a0, 0, 0, 0); \
        }                                                                         \
        float qv[16];                                                             \
        float2v s2 = (float2v){s, s};                                             \
        _Pragma("unroll")                                                         \
        for (int h = 0; h < 8; ++h) {                                             \
            float2v p2 = (float2v){PC[2*h], PC[2*h+1]};                           \
            float2v q2 = p2 * s2;                                                 \
            qv[2*h] = q2.x; qv[2*h+1] = q2.y;                                     \
        }                                                                         \
        bool cap = ((t) == lenl);                                                 \
        ncap = cap ? acc[2][3] : ncap;  /* END=51 at it=2,r=3 on q==2 lanes */    \
        lcap = cap ? lsum_pre : lcap;                                             \
        int myeb = (int)((__float_as_uint(acc[0][0]) >> 23) & 0xffu);             \
        ebp = __builtin_amdgcn_ds_bpermute(addrB, myeb);                          \
        _Pragma("unroll")                                                         \
        for (int h = 0; h < 8; ++h) {                                             \
            float2v d2 = (float2v){acc[h>>1][(h&1)*2], acc[h>>1][(h&1)*2+1]};     \
            float2v q2 = (float2v){qv[2*h], qv[2*h+1]};                           \
            float2v e2 = d2 * q2;                                                 \
            E[2*h] = e2.x; E[2*h+1] = e2.y;                                       \
        }                                                                         \
        int _tn = (t) + 8; _tn = (_tn < SS) ? _tn : (SS - 1);                     \
        LOADP4(PC, _tn);                                                          \
    } while (0)

        for (int t0 = 1; t0 <= SS; t0 += 8) {
            STEP(r0, t0);
            STEP(r1, t0 + 1);
            STEP(r2, t0 + 2);
            STEP(r3, t0 + 3);
            STEP(r4, t0 + 4);
            STEP(r5, t0 + 5);
            STEP(r6, t0 + 6);
            STEP(r7, t0 + 7);
        }
#undef STEP
#undef LOADP4

        norm_e = (__builtin_amdgcn_logf(ncap) - (float)lcap) * (1.0f / L2E);
    } else {
        // wave 1: gold scores, 4 lanes per batch
        const int lb2 = lane >> 2;
        const int ph  = lane & 3;
        const int bb  = g * 16 + lb2;
        const int len = lens[bb];
        const size_t base = (size_t)bb * SS;
        float un2 = 0.f, bi = 0.f;
        for (int t = ph; t < len; t += 4) {
            int lab = labels[base + t];
            un2 += __builtin_amdgcn_logf(PE[(base + t) * 64 + lab]); // log2
            int prev = (t == 0) ? LBL : labels[base + t - 1];
            bi += T[lab * NL + prev];
        }
        float gsum = un2 * (1.0f / L2E) + bi;
        gsum += __shfl_xor(gsum, 1, 64);
        gsum += __shfl_xor(gsum, 2, 64);
        if (ph == 0) {
            gsum += T[(NL - 1) * NL + labels[base + len - 1]];
            gold_sh[lb2] = gsum;
        }
    }

    __syncthreads();
    if (wv == 0 && q == 2) { // lanes 32..47 hold the END-row norm
        float v = norm_e - gold_sh[b];
        v += __shfl_xor(v, 1, 64);
        v += __shfl_xor(v, 2, 64);
        v += __shfl_xor(v, 4, 64);
        v += __shfl_xor(v, 8, 64);
        if (b == 0) atomicAdd(out, v);
    }
}

// ---------------------------------------------------------------------------
extern "C" void kernel_launch(void* const* d_in, const int* in_sizes, int n_in,
                              void* d_out, int out_size, void* d_ws, size_t ws_size,
                              hipStream_t stream) {
    const float* A      = (const float*)d_in[0]; // inputs [128,512,1024]
    const float* W      = (const float*)d_in[1]; // [50,1024]
    const float* bias   = (const float*)d_in[2]; // [50]
    const float* T      = (const float*)d_in[3]; // [52,52]
    const int*   lens   = (const int*)d_in[4];   // [128]
    const int*   labels = (const int*)d_in[5];   // [128,512]
    float* out = (float*)d_out;

    float* PEp = (float*)d_ws;                               // 65536*64*4 = 16.78 MB
    unsigned short* Wbf = (unsigned short*)((char*)d_ws + (size_t)65536 * 64 * 4); // 131 KB

    hipMemsetAsync(d_out, 0, sizeof(float), stream);
    wconv<<<dim3(256), dim3(256), 0, stream>>>(W, Wbf);
    gemm_pe<<<dim3((BB * SS) / 64), dim3(256), 0, stream>>>(A, Wbf, bias, PEp);
    crf_fwd<<<dim3(8), dim3(128), 0, stream>>>(PEp, T, lens, labels, out);
}

// Round 3
// 442.323 us; speedup vs baseline: 1.1228x; 1.1228x over previous
//
#include <hip/hip_runtime.h>
#include <stdint.h>

#define LBL 50
#define NL 52
#define L2E 1.4426950408889634f
#define BB 128
#define SS 512
#define DD 1024

typedef __attribute__((ext_vector_type(8))) short short8;
typedef __attribute__((ext_vector_type(4))) float float4v;

union S8U { unsigned int u[4]; short8 s; };

static __device__ __forceinline__ unsigned int f2bf(float f) {
    union { float f; unsigned int u; } v; v.f = f;
    unsigned int r = v.u + 0x7fffu + ((v.u >> 16) & 1u);
    return r >> 16;
}

// ---------------------------------------------------------------------------
// Kernel 0: W [50,1024] f32 -> Wbf [64,1024] bf16 (rows 50..63 zero), rounded.
// ---------------------------------------------------------------------------
__global__ __launch_bounds__(256) void wconv(
    const float* __restrict__ W, unsigned short* __restrict__ Wbf)
{
    int i = blockIdx.x * 256 + threadIdx.x;   // 0..65535
    int r = i >> 10, c = i & 1023;
    float v = (r < LBL) ? W[r * DD + c] : 0.f;
    Wbf[i] = (unsigned short)f2bf(v);
}

// ---------------------------------------------------------------------------
// Kernel 1: PEp[r, c] = exp(sum_d A[r,d]*W[c,d] + b[c]) for c<50, else 0.
// ---------------------------------------------------------------------------
__global__ __launch_bounds__(256) void gemm_pe(
    const float* __restrict__ A,            // [65536,1024]
    const unsigned short* __restrict__ Wbf, // [64,1024] bf16
    const float* __restrict__ bias,         // [50]
    float* __restrict__ PEp)                // [65536,64]
{
    const int tid  = threadIdx.x;
    const int lane = tid & 63;
    const int wv   = tid >> 6;
    const int mrow = lane & 15;
    const int quad = lane >> 4;
    const int row  = blockIdx.x * 64 + wv * 16 + mrow;

    const uint4* arow = (const uint4*)(A + (size_t)row * DD);

    float4v acc[4];
#pragma unroll
    for (int i = 0; i < 4; ++i) acc[i] = (float4v){0.f, 0.f, 0.f, 0.f};

#pragma unroll 4
    for (int kc = 0; kc < DD; kc += 32) {
        uint4 u0 = arow[(kc >> 2) + quad * 2];
        uint4 u1 = arow[(kc >> 2) + quad * 2 + 1];
        S8U a;
        a.u[0] = __builtin_amdgcn_perm(u0.y, u0.x, 0x07060302u);
        a.u[1] = __builtin_amdgcn_perm(u0.w, u0.z, 0x07060302u);
        a.u[2] = __builtin_amdgcn_perm(u1.y, u1.x, 0x07060302u);
        a.u[3] = __builtin_amdgcn_perm(u1.w, u1.z, 0x07060302u);
#pragma unroll
        for (int nt = 0; nt < 4; ++nt) {
            short8 bf = *(const short8*)(Wbf + (size_t)(nt * 16 + mrow) * DD + kc + quad * 8);
            acc[nt] = __builtin_amdgcn_mfma_f32_16x16x32_bf16(a.s, bf, acc[nt], 0, 0, 0);
        }
    }
    const int r0 = blockIdx.x * 64 + wv * 16 + quad * 4;
#pragma unroll
    for (int nt = 0; nt < 4; ++nt) {
        int col = nt * 16 + mrow;
        float bv = (col < LBL) ? bias[col] : 0.f;
#pragma unroll
        for (int rr = 0; rr < 4; ++rr) {
            float val = (col < LBL) ? __builtin_amdgcn_exp2f((acc[nt][rr] + bv) * L2E) : 0.f;
            PEp[(size_t)(r0 + rr) * 64 + col] = val;
        }
    }
}

// ---------------------------------------------------------------------------
// Kernel 2: segmented CRF scan, stage 1 (segment matrix products).
// Task (s,k): M = Prod_{t=t0+31..t0} G~_t where G~_t = diag(PE[t]) * eT for
// t < len, else I. 2048 tasks x 1 wave: full 64x64x64 multiply per step via
// 32 MFMA; sigma-permuted constant A (R1-verified) makes C rows land in next
// B-frag k-slots per N-tile (lane-local perm repack). Per-multiply power-of-2
// rescale via readfirstlane exponent (wave-uniform scale, no LDS).
// Output: M in B-frag-natural layout segm[sk][n][j] = M[j][n] (bf16), plus
// csum (stored = true * 2^csum).
// ---------------------------------------------------------------------------
__global__ __launch_bounds__(64) void crf_seg(
    const float* __restrict__ PE,      // [65536,64]
    const float* __restrict__ T,       // [52,52]
    const int*   __restrict__ lens,    // [128]
    unsigned short* __restrict__ segm, // [2048][64][64] bf16
    int* __restrict__ segc)            // [2048]
{
    const int sk   = blockIdx.x;
    const int s    = sk >> 4;
    const int k    = sk & 15;
    const int lane = threadIdx.x & 63;
    const int b    = lane & 15;
    const int q    = lane >> 4;
    const int L    = lens[s];
    const int t0   = 1 + k * 32;
    int tend = t0 + 31; if (L - 1 < tend) tend = L - 1;   // inclusive

    // constant A-frags: sigma-permuted e^T (verbatim from R1-verified kernel)
    short8 afr[4][2];
#pragma unroll
    for (int it = 0; it < 4; ++it) {
        int i = (b >> 2) * 8 + (b & 3) + 4 * (it & 1) + 32 * (it >> 1);
#pragma unroll
        for (int jt = 0; jt < 2; ++jt) {
            S8U pk;
#pragma unroll
            for (int h = 0; h < 4; ++h) {
                int k0 = jt * 32 + q * 8 + 2 * h;
                float v0 = (i < NL && k0     < NL) ? __builtin_amdgcn_exp2f(T[i * NL + k0]     * L2E) : 0.f;
                float v1 = (i < NL && k0 + 1 < NL) ? __builtin_amdgcn_exp2f(T[i * NL + k0 + 1] * L2E) : 0.f;
                pk.u[h] = f2bf(v0) | (f2bf(v1) << 16);
            }
            afr[it][jt] = pk.s;
        }
    }

    // M = I in B-frag layout: bfr[nt][kc] holds M[kk][n], kk=kc*32+q*8+(0..7),
    // n = nt*16+b, bf16 pairs (lo=even kk).
    S8U bfr[4][2];
#pragma unroll
    for (int nt = 0; nt < 4; ++nt)
#pragma unroll
        for (int kc = 0; kc < 2; ++kc)
#pragma unroll
            for (int u = 0; u < 4; ++u) {
                int kk = kc * 32 + q * 8 + 2 * u;
                int n  = nt * 16 + b;
                unsigned int v = 0;
                if (kk == n)     v |= 0x3F80u;
                if (kk + 1 == n) v |= (0x3F80u << 16);
                bfr[nt][kc].u[u] = v;
            }

    int csum = 0;
    if (t0 <= tend) {
        const float* prow = PE + (size_t)(s * SS + t0) * 64 + q * 8;
        float4 f0 = *(const float4*)(prow);
        float4 f1 = *(const float4*)(prow + 4);
        float4 f2 = *(const float4*)(prow + 32);
        float4 f3 = *(const float4*)(prow + 36);
        for (int t = t0; t <= tend; ++t) {
            // prefetch next row (worst case reads into Wbf region: allocated, unused)
            const float* pn = prow + 64;
            float4 g0 = *(const float4*)(pn);
            float4 g1 = *(const float4*)(pn + 4);
            float4 g2 = *(const float4*)(pn + 32);
            float4 g3 = *(const float4*)(pn + 36);

            const float4v zz = (float4v){0.f, 0.f, 0.f, 0.f};
            float4v acc[4][4];
#pragma unroll
            for (int it = 0; it < 4; ++it)
#pragma unroll
                for (int nt = 0; nt < 4; ++nt)
                    acc[it][nt] = __builtin_amdgcn_mfma_f32_16x16x32_bf16(afr[it][0], bfr[nt][0].s, zz, 0, 0, 0);
#pragma unroll
            for (int it = 0; it < 4; ++it)
#pragma unroll
                for (int nt = 0; nt < 4; ++nt)
                    acc[it][nt] = __builtin_amdgcn_mfma_f32_16x16x32_bf16(afr[it][1], bfr[nt][1].s, acc[it][nt], 0, 0, 0);

            // wave-uniform power-of-2 rescale (d=1 feedback, as proven scheme)
            int myeb = (int)((__float_as_uint(acc[0][0][0]) >> 23) & 0xffu);
            int eb   = __builtin_amdgcn_readfirstlane(myeb);
            float ss = __uint_as_float((unsigned int)(254 - eb) << 23); // 2^(127-eb)
            csum += 127 - eb;

            // pvs[k'] = PE-rowscale * ss, k' = it*4+r, label = q*8+r+4(it&1)+32(it>>1)
            float pvs[16];
            pvs[0]  = f0.x * ss; pvs[1]  = f0.y * ss; pvs[2]  = f0.z * ss; pvs[3]  = f0.w * ss;
            pvs[4]  = f1.x * ss; pvs[5]  = f1.y * ss; pvs[6]  = f1.z * ss; pvs[7]  = f1.w * ss;
            pvs[8]  = f2.x * ss; pvs[9]  = f2.y * ss; pvs[10] = f2.z * ss; pvs[11] = f2.w * ss;
            pvs[12] = f3.x * ss; pvs[13] = f3.y * ss; pvs[14] = f3.z * ss; pvs[15] = f3.w * ss;

            // repack per N-tile: new bfr[nt][kc].u[u] = pack(E[kc*8+2u], E[kc*8+2u+1])
            // with E[k'] = acc[k'>>2][nt][k'&3] * pvs[k']  (truncating bf16 pack)
#pragma unroll
            for (int nt = 0; nt < 4; ++nt) {
                float ev[16];
#pragma unroll
                for (int kp = 0; kp < 16; ++kp)
                    ev[kp] = acc[kp >> 2][nt][kp & 3] * pvs[kp];
#pragma unroll
                for (int kc = 0; kc < 2; ++kc)
#pragma unroll
                    for (int u = 0; u < 4; ++u)
                        bfr[nt][kc].u[u] = __builtin_amdgcn_perm(
                            __float_as_uint(ev[kc * 8 + 2 * u + 1]),
                            __float_as_uint(ev[kc * 8 + 2 * u]), 0x07060302u);
            }

            f0 = g0; f1 = g1; f2 = g2; f3 = g3;
            prow = pn;
        }
    }

    // store M (B-frag-natural): segm[sk][n][j] = M[j][n]
    unsigned short* ob = segm + (size_t)sk * 4096;
#pragma unroll
    for (int nt = 0; nt < 4; ++nt)
#pragma unroll
        for (int kc = 0; kc < 2; ++kc) {
            uint4 st; st.x = bfr[nt][kc].u[0]; st.y = bfr[nt][kc].u[1];
            st.z = bfr[nt][kc].u[2]; st.w = bfr[nt][kc].u[3];
            *(uint4*)(ob + (nt * 16 + b) * 64 + kc * 32 + q * 8) = st;
        }
    if (lane == 0) segc[sk] = csum;
}

// ---------------------------------------------------------------------------
// Kernel 3: segmented CRF scan, stage 2 (fold + gold + loss). 1 block/seq.
// Wave0: w^T <- w^T * S_k for k=15..0 (w0 = e^{T[END,:]}), then dot with
// E1 = PE[row0] .* e^{T[:,START]}; norm = (log2(dot) - F)/L2E.
// Segment B-frags load back with the exact store addressing (no transpose).
// Redistribution of w_new to A-frag slots: 16 ds_bpermute (addr = j*4, src =
// own-q slot so source lane j holds w_new[j]).
// Wave1: gold score (64 lanes over t). Block writes atomicAdd(norm - gold).
// ---------------------------------------------------------------------------
__global__ __launch_bounds__(128) void crf_comb(
    const float* __restrict__ PE,
    const float* __restrict__ T,
    const int*   __restrict__ lens,
    const int*   __restrict__ labels,
    const unsigned short* __restrict__ segm,
    const int*   __restrict__ segc,
    float* __restrict__ out)
{
    const int s    = blockIdx.x;
    const int tid  = threadIdx.x;
    const int lane = tid & 63;
    const int wv   = tid >> 6;

    __shared__ float gold_sh;
    float norm_ln = 0.f;

    if (wv == 1) {
        const int len = lens[s];
        const size_t base = (size_t)s * SS;
        float un2 = 0.f, bi = 0.f;
        for (int t = lane; t < len; t += 64) {
            int lab  = labels[base + t];
            int prev = (t == 0) ? LBL : labels[base + t - 1];
            un2 += __builtin_amdgcn_logf(PE[(base + t) * 64 + lab]); // log2
            bi  += T[lab * NL + prev];
        }
        float g = un2 * (1.0f / L2E) + bi;
        g += __shfl_xor(g, 1, 64);
        g += __shfl_xor(g, 2, 64);
        g += __shfl_xor(g, 4, 64);
        g += __shfl_xor(g, 8, 64);
        g += __shfl_xor(g, 16, 64);
        g += __shfl_xor(g, 32, 64);
        if (lane == 0) {
            g += T[(NL - 1) * NL + labels[base + len - 1]];
            gold_sh = g;
        }
    } else {
        const int b = lane & 15, q = lane >> 4;
        const float4v zz = (float4v){0.f, 0.f, 0.f, 0.f};

        // w0 A-frags (replicated across b): aw[kc] = w[kc*32+q*8+(0..7)]
        S8U aw[2];
#pragma unroll
        for (int kc = 0; kc < 2; ++kc)
#pragma unroll
            for (int u = 0; u < 4; ++u) {
                int j0 = kc * 32 + q * 8 + 2 * u;
                float v0 = (j0     < NL) ? __builtin_amdgcn_exp2f(T[(NL - 1) * NL + j0]     * L2E) : 0.f;
                float v1 = (j0 + 1 < NL) ? __builtin_amdgcn_exp2f(T[(NL - 1) * NL + j0 + 1] * L2E) : 0.f;
                aw[kc].u[u] = f2bf(v0) | (f2bf(v1) << 16);
            }

        int F = 0;
        float sv0 = 0.f, sv1 = 0.f, sv2 = 0.f, sv3 = 0.f;

        for (int kk = 15; kk >= 0; --kk) {
            const unsigned short* mb = segm + (size_t)(s * 16 + kk) * 4096;
            S8U bfr[4][2];
#pragma unroll
            for (int nt = 0; nt < 4; ++nt)
#pragma unroll
                for (int kc = 0; kc < 2; ++kc) {
                    uint4 ld = *(const uint4*)(mb + (nt * 16 + b) * 64 + kc * 32 + q * 8);
                    bfr[nt][kc].u[0] = ld.x; bfr[nt][kc].u[1] = ld.y;
                    bfr[nt][kc].u[2] = ld.z; bfr[nt][kc].u[3] = ld.w;
                }
            float4v acc[4];
#pragma unroll
            for (int nt = 0; nt < 4; ++nt)
                acc[nt] = __builtin_amdgcn_mfma_f32_16x16x32_bf16(aw[0].s, bfr[nt][0].s, zz, 0, 0, 0);
#pragma unroll
            for (int nt = 0; nt < 4; ++nt)
                acc[nt] = __builtin_amdgcn_mfma_f32_16x16x32_bf16(aw[1].s, bfr[nt][1].s, acc[nt], 0, 0, 0);

            int myeb = (int)((__float_as_uint(acc[0][0]) >> 23) & 0xffu);
            int eb   = __builtin_amdgcn_readfirstlane(myeb);
            float ssc = __uint_as_float((unsigned int)(254 - eb) << 23);
            F += segc[s * 16 + kk] + (127 - eb);

            sv0 = acc[0][0] * ssc; sv1 = acc[1][0] * ssc;
            sv2 = acc[2][0] * ssc; sv3 = acc[3][0] * ssc;

            if (kk == 0) break;

            // own-q slot; source lane j (= q'*16+b') then holds w_new[j]
            float svq = (q & 2) ? ((q & 1) ? sv3 : sv2) : ((q & 1) ? sv1 : sv0);
            int svqi = __float_as_int(svq);
#pragma unroll
            for (int kc = 0; kc < 2; ++kc)
#pragma unroll
                for (int u = 0; u < 4; ++u) {
                    int j0 = kc * 32 + q * 8 + 2 * u;
                    int w0i = __builtin_amdgcn_ds_bpermute(j0 * 4,       svqi);
                    int w1i = __builtin_amdgcn_ds_bpermute((j0 + 1) * 4, svqi);
                    aw[kc].u[u] = __builtin_amdgcn_perm((unsigned)w1i, (unsigned)w0i, 0x07060302u);
                }
        }

        // dot with E1[n] = PE[seq row 0][n] * e^{T[n][START]}
        float dp = 0.f;
        const float* pe0 = PE + (size_t)s * SS * 64;
        float svs[4] = {sv0, sv1, sv2, sv3};
#pragma unroll
        for (int nt = 0; nt < 4; ++nt) {
            int n = nt * 16 + b;
            float e1 = (n < NL) ? pe0[n] * __builtin_amdgcn_exp2f(T[n * NL + LBL] * L2E) : 0.f;
            dp += svs[nt] * e1;
        }
        dp += __shfl_xor(dp, 1, 64);
        dp += __shfl_xor(dp, 2, 64);
        dp += __shfl_xor(dp, 4, 64);
        dp += __shfl_xor(dp, 8, 64);
        norm_ln = (__builtin_amdgcn_logf(dp) - (float)F) * (1.0f / L2E);
    }

    __syncthreads();
    if (tid == 0) atomicAdd(out, norm_ln - gold_sh);
}

// ---------------------------------------------------------------------------
extern "C" void kernel_launch(void* const* d_in, const int* in_sizes, int n_in,
                              void* d_out, int out_size, void* d_ws, size_t ws_size,
                              hipStream_t stream) {
    const float* A      = (const float*)d_in[0]; // inputs [128,512,1024]
    const float* W      = (const float*)d_in[1]; // [50,1024]
    const float* bias   = (const float*)d_in[2]; // [50]
    const float* T      = (const float*)d_in[3]; // [52,52]
    const int*   lens   = (const int*)d_in[4];   // [128]
    const int*   labels = (const int*)d_in[5];   // [128,512]
    float* out = (float*)d_out;

    float* PEp = (float*)d_ws;                                              // 16.78 MB
    unsigned short* Wbf  = (unsigned short*)((char*)d_ws + (size_t)65536 * 64 * 4); // 131 KB
    unsigned short* segm = (unsigned short*)((char*)d_ws + ((size_t)32 << 20));     // 16.78 MB
    int*            segc = (int*)((char*)d_ws + ((size_t)56 << 20));                // 8 KB

    hipMemsetAsync(d_out, 0, sizeof(float), stream);
    wconv<<<dim3(256), dim3(256), 0, stream>>>(W, Wbf);
    gemm_pe<<<dim3((BB * SS) / 64), dim3(256), 0, stream>>>(A, Wbf, bias, PEp);
    crf_seg<<<dim3(2048), dim3(64), 0, stream>>>(PEp, T, lens, segm, segc);
    crf_comb<<<dim3(128), dim3(128), 0, stream>>>(PEp, T, lens, labels, segm, segc, out);
}